// Round 10
// baseline (374.672 us; speedup 1.0000x reference)
//
#include <hip/hip_runtime.h>
#include <math.h>

#define EPS 1e-5f

typedef __attribute__((ext_vector_type(8))) short short8;
typedef __attribute__((ext_vector_type(4))) float float4v;

__device__ __forceinline__ bool better(float v1, int i1, float v2, int i2) {
  return (v1 > v2) || (v1 == v2 && i1 < i2);
}

__device__ __forceinline__ unsigned short f2bf(float f) {
  unsigned int u = __float_as_uint(f);
  unsigned int r = u + 0x7fffu + ((u >> 16) & 1u);
  return (unsigned short)(r >> 16);
}
__device__ __forceinline__ float bf2f(unsigned short s) {
  return __uint_as_float(((unsigned int)s) << 16);
}

// Row-coefficient table: RCtab[situation][kr][dr]
// situation: 0 = even phase (R=2i), 1 = odd phase (R=2i+1),
//            2 = lo edge (R=0, base row 0), 3 = hi edge (R=255, base row 125)
__device__ __constant__ float RCtab[4][3][3] = {
  {{0.75f, 0.25f, 0.f}, {0.25f, 0.75f, 0.f}, {0.f, 0.75f, 0.25f}},
  {{0.25f, 0.75f, 0.f}, {0.f, 0.75f, 0.25f}, {0.f, 0.25f, 0.75f}},
  {{0.f, 0.f, 0.f},     {1.0f, 0.f, 0.f},    {0.75f, 0.25f, 0.f}},
  {{0.f, 0.25f, 0.75f}, {0.f, 0.f, 1.0f},    {0.f, 0.f, 0.f}},
};

// ---------------------------------------------------------------------------
// K0: precompute (a) 4 interior phase filters as bf16 hi/lo for MFMA B-frags,
//     (b) 16 (row-sit x col-sit) fp32 filter sets for the border fixup.
// ---------------------------------------------------------------------------
__global__ __launch_bounds__(256) void k_wprep(const float* __restrict__ w1,
                                               unsigned short* __restrict__ Wphase,
                                               float* __restrict__ EdgeEff) {
  int e = blockIdx.x * 256 + threadIdx.x;
  if (e < 147456) {
    int cil = e & 31, co = (e >> 5) & 63, ck = (e >> 11) & 1;
    int tap = (e >> 12) % 9, ph = e / 36864;     // ph = pr*2+pc
    int pr = ph >> 1, pc = ph & 1;
    int dr = tap / 3, dc = tap % 3;
    int ci = ck * 32 + cil;
    const float* wp = w1 + (co * 64 + ci) * 9;
    float eff = 0.f;
    #pragma unroll
    for (int kr = 0; kr < 3; ++kr)
      #pragma unroll
      for (int kc = 0; kc < 3; ++kc)
        eff += wp[kr * 3 + kc] * RCtab[pr][kr][dr] * RCtab[pc][kc][dc];
    unsigned short hi = f2bf(eff);
    unsigned short lo = f2bf(eff - bf2f(hi));
    int g = (ph * 9 + tap) * 2 + ck;
    Wphase[g * 4096 + co * 32 + cil] = hi;
    Wphase[g * 4096 + 2048 + co * 32 + cil] = lo;
  } else if (e < 147456 + 589824) {
    int e2 = e - 147456;
    int co = e2 & 63, tap = (e2 >> 6) % 9, ci = (e2 / 576) & 63, set = e2 / 36864;
    int rs = set >> 2, cs = set & 3;
    int dr = tap / 3, dc = tap % 3;
    const float* wp = w1 + (co * 64 + ci) * 9;
    float eff = 0.f;
    #pragma unroll
    for (int kr = 0; kr < 3; ++kr)
      #pragma unroll
      for (int kc = 0; kc < 3; ++kc)
        eff += wp[kr * 3 + kc] * RCtab[rs][kr][dr] * RCtab[cs][kc][dc];
    EdgeEff[set * 36864 + (ci * 9 + tap) * 64 + co] = eff;
  }
}

// ---------------------------------------------------------------------------
// K1: conv(upsample) via 4 phase filters. 512 threads = 8 waves: wave w has
// phase = w&3, half = w>>2 owning mt = half*2+{0,1}. Per-accumulator FP chains
// are byte-identical to the proven 256-thread version (R6/R7) — pure spatial
// split for 2 waves/SIMD latency hiding. Staging/XS layout untouched.
// ---------------------------------------------------------------------------
__global__ __launch_bounds__(512, 1) void k_front(
    const float* __restrict__ x, const unsigned short* __restrict__ Wphase,
    const float* __restrict__ b1, const float* __restrict__ g1,
    const float* __restrict__ be1, const float* __restrict__ m1,
    const float* __restrict__ v1, const float* __restrict__ w2,
    const float* __restrict__ g2, const float* __restrict__ be2,
    const float* __restrict__ m2, const float* __restrict__ v2,
    float* __restrict__ xf)
{
  // 8 staging buffers [b][ck][hl] of 100 pos x 40 shorts = 64000 B,
  // aliased by epilogue V fp32 256x65 = 66560 B.
  __shared__ __align__(16) char lds[66560];
  unsigned short* XS = (unsigned short*)lds;
  float* V = (float*)lds;
  __shared__ float w2s[512];
  __shared__ float A1s[64], C1s[64];
  __shared__ float s2s[8], sh2s[8];

  const int tid = threadIdx.x;
  const int bx = blockIdx.x, by = blockIdx.y, bz = blockIdx.z;

  if (tid < 512) w2s[tid] = w2[tid];
  if (tid < 64) {
    float sc = g1[tid] * rsqrtf(v1[tid] + EPS);
    A1s[tid] = sc;
    C1s[tid] = sc * (b1[tid] - m1[tid]) + be1[tid];
  }
  if (tid < 8) {
    float sc = g2[tid] * rsqrtf(v2[tid] + EPS);
    s2s[tid] = sc;
    sh2s[tid] = be2[tid] - m2[tid] * sc;
  }

  // --- stage clamped 10x10 x-tile, 64 ci, hi/lo, both batches (unchanged) ---
  if (tid < 200) {
    int ckh = tid / 100;
    int pos = tid % 100;
    int r = pos / 10, c = pos % 10;
    int rr = min(max(by * 8 - 1 + r, 0), 127);
    int cc = min(max(bx * 8 - 1 + c, 0), 127);
    #pragma unroll
    for (int b = 0; b < 2; ++b) {
      const float* xp = x + (size_t)((bz * 2 + b) * 64 + ckh * 32) * 16384 + rr * 128 + cc;
      unsigned int* dh = (unsigned int*)(XS + ((b * 2 + ckh) * 2 + 0) * 4000) + pos * 20;
      unsigned int* dl = (unsigned int*)(XS + ((b * 2 + ckh) * 2 + 1) * 4000) + pos * 20;
      for (int cp = 0; cp < 16; ++cp) {
        float v0 = xp[(size_t)(2 * cp) * 16384];
        float v1x = xp[(size_t)(2 * cp + 1) * 16384];
        unsigned short h0 = f2bf(v0), h1 = f2bf(v1x);
        unsigned short l0 = f2bf(v0 - bf2f(h0)), l1 = f2bf(v1x - bf2f(h1));
        dh[cp] = (unsigned int)h0 | ((unsigned int)h1 << 16);
        dl[cp] = (unsigned int)l0 | ((unsigned int)l1 << 16);
      }
    }
  }
  __syncthreads();

  const int l = tid & 63, w = tid >> 6;      // w in 0..7
  const int wv = w & 3;                      // phase = pr*2+pc
  const int half = w >> 2;                   // mt half: 0 -> mt {0,1}, 1 -> {2,3}
  const int pr = wv >> 1, pc = wv & 1;
  const int lm = l & 15, q = l >> 4;
  const int arow = lm >> 3, acol = lm & 7;

  float4v acc[2][2][4];
  #pragma unroll
  for (int b = 0; b < 2; ++b)
    #pragma unroll
    for (int mtp = 0; mtp < 2; ++mtp)
      #pragma unroll
      for (int nt = 0; nt < 4; ++nt) acc[b][mtp][nt] = (float4v){0.f, 0.f, 0.f, 0.f};

  #pragma unroll
  for (int ck = 0; ck < 2; ++ck) {
    #pragma unroll
    for (int tap = 0; tap < 9; ++tap) {
      const int dr = tap / 3, dc = tap % 3;
      const unsigned short* wb = Wphase + ((wv * 9 + tap) * 2 + ck) * 4096;
      short8 bh[4], bl[4];
      #pragma unroll
      for (int nt = 0; nt < 4; ++nt) {
        int off = (nt * 16 + lm) * 32 + q * 8;
        bh[nt] = *(const short8*)(wb + off);
        bl[nt] = *(const short8*)(wb + 2048 + off);
      }
      #pragma unroll
      for (int b = 0; b < 2; ++b) {
        const unsigned short* XH = XS + ((b * 2 + ck) * 2 + 0) * 4000;
        const unsigned short* XL = XS + ((b * 2 + ck) * 2 + 1) * 4000;
        #pragma unroll
        for (int mtp = 0; mtp < 2; ++mtp) {
          int gmt = half * 2 + mtp;
          int pos = (gmt * 2 + arow + dr) * 10 + acol + dc;
          short8 ah = *(const short8*)(XH + pos * 40 + q * 8);
          short8 al = *(const short8*)(XL + pos * 40 + q * 8);
          #pragma unroll
          for (int nt = 0; nt < 4; ++nt) {
            acc[b][mtp][nt] = __builtin_amdgcn_mfma_f32_16x16x32_bf16(ah, bh[nt], acc[b][mtp][nt], 0, 0, 0);
            acc[b][mtp][nt] = __builtin_amdgcn_mfma_f32_16x16x32_bf16(al, bh[nt], acc[b][mtp][nt], 0, 0, 0);
            acc[b][mtp][nt] = __builtin_amdgcn_mfma_f32_16x16x32_bf16(ah, bl[nt], acc[b][mtp][nt], 0, 0, 0);
          }
        }
      }
    }
  }

  // --- epilogue per batch: acc -> V (BN1+ReLU) -> fp32 1x1 + BN2 + filter ---
  #pragma unroll
  for (int b = 0; b < 2; ++b) {
    __syncthreads();   // staging (b=0) or previous V reads (b=1) complete
    #pragma unroll
    for (int mtp = 0; mtp < 2; ++mtp) {
      int gmt = half * 2 + mtp;
      #pragma unroll
      for (int nt = 0; nt < 4; ++nt) {
        int co = nt * 16 + lm;
        float A = A1s[co], Cc = C1s[co];
        #pragma unroll
        for (int r = 0; r < 4; ++r) {
          int p = gmt * 16 + q * 4 + r;              // pixel within phase (8x8)
          int ur = 2 * (p >> 3) + pr, uc = 2 * (p & 7) + pc;
          V[(ur * 16 + uc) * 65 + co] = fmaxf(fmaf(A, acc[b][mtp][nt][r], Cc), 0.f);
        }
      }
    }
    __syncthreads();
    if (tid < 256) {
      float a2[8];
      #pragma unroll
      for (int c2 = 0; c2 < 8; ++c2) a2[c2] = 0.f;
      const float* vp = &V[tid * 65];
      for (int co = 0; co < 64; ++co) {
        float xv = vp[co];
        #pragma unroll
        for (int c2 = 0; c2 < 8; ++c2) a2[c2] = fmaf(w2s[c2 * 64 + co], xv, a2[c2]);
      }
      int ur = tid >> 4, uc = tid & 15;
      int batch = bz * 2 + b;
      #pragma unroll
      for (int c2 = 0; c2 < 8; ++c2) {
        float y = fmaf(s2s[c2], a2[c2], sh2s[c2]);
        float o = (y > 1.0f) ? y : 0.f;
        xf[((batch * 8 + c2) * 256 + by * 16 + ur) * 256 + bx * 16 + uc] = o;
      }
    }
  }
}

// ---------------------------------------------------------------------------
// k_fix v3 helpers (proven R9).
// ---------------------------------------------------------------------------
template<int S_IS_DR>
__device__ __forceinline__ void fix_loop(const float* __restrict__ Ecom,
                                         const float* __restrict__ Xs,
                                         int base, float acc[8]) {
  for (int ci = 0; ci < 64; ++ci) {
    const float* xsrow = Xs + ci * 60;
    float run0[12], run1[12], run2[12];
    #pragma unroll
    for (int j = 0; j < 3; ++j) {
      ((float4*)run0)[j] = ((const float4*)(xsrow + base))[j];
      ((float4*)run1)[j] = ((const float4*)(xsrow + 20 + base))[j];
      ((float4*)run2)[j] = ((const float4*)(xsrow + 40 + base))[j];
    }
    float wt[9];
    #pragma unroll
    for (int tap = 0; tap < 9; ++tap) wt[tap] = Ecom[(ci * 9 + tap) * 64];
    #pragma unroll
    for (int tap = 0; tap < 9; ++tap) {
      const int dr = tap / 3, dc = tap % 3;
      const int s = S_IS_DR ? dr : dc;
      const int d = S_IS_DR ? dc : dr;
      const float* run = (s == 0) ? run0 : ((s == 1) ? run1 : run2);
      #pragma unroll
      for (int k = 0; k < 8; ++k)
        acc[k] = fmaf(wt[tap], run[k + d], acc[k]);
    }
  }
}

__device__ __forceinline__ float corner_acc(const float* __restrict__ Ecor,
                                            const float* __restrict__ Xs,
                                            int pcor) {
  float a = 0.f;
  for (int ci = 0; ci < 64; ++ci) {
    const float* xsrow = Xs + ci * 60;
    #pragma unroll
    for (int tap = 0; tap < 9; ++tap) {
      const int dr = tap / 3, dc = tap % 3;
      a = fmaf(Ecor[(ci * 9 + tap) * 64], xsrow[dr * 20 + pcor + dc], a);
    }
  }
  return a;
}

// ---------------------------------------------------------------------------
// K2: border fixup v3 (proven R9).
// ---------------------------------------------------------------------------
__global__ __launch_bounds__(256, 1) void k_fix(
    const float* __restrict__ x, const float* __restrict__ EdgeEff,
    const float* __restrict__ b1, const float* __restrict__ g1,
    const float* __restrict__ be1, const float* __restrict__ m1,
    const float* __restrict__ v1, const float* __restrict__ w2,
    const float* __restrict__ g2, const float* __restrict__ be2,
    const float* __restrict__ m2, const float* __restrict__ v2,
    float* __restrict__ xf)
{
  __shared__ __align__(16) float Xs[64 * 60];   // [ci][slot3][fast20]
  __shared__ float w2s[512];
  __shared__ float A1s[64], C1s[64];
  __shared__ float s2s[8], sh2s[8];

  const int tid = threadIdx.x;
  const int seg = blockIdx.x, line = blockIdx.y, bz = blockIdx.z;
  const bool is01 = (line < 2);

  for (int i = tid; i < 512; i += 256) w2s[i] = w2[i];
  if (tid < 64) {
    float sc = g1[tid] * rsqrtf(v1[tid] + EPS);
    A1s[tid] = sc;
    C1s[tid] = sc * (b1[tid] - m1[tid]) + be1[tid];
  }
  if (tid < 8) {
    float sc = g2[tid] * rsqrtf(v2[tid] + EPS);
    s2s[tid] = sc;
    sh2s[tid] = be2[tid] - m2[tid] * sc;
  }

  const int base0 = seg * 16 - 1;
  for (int e = tid; e < 3840; e += 256) {
    int f = e % 20;
    int slot = (e / 20) % 3;
    int ci = e / 60;
    int row, col;
    if (is01) { row = (line == 0 ? 0 : 125) + slot; col = min(max(base0 + f, 0), 127); }
    else      { col = (line == 2 ? 0 : 125) + slot; row = min(max(base0 + f, 0), 127); }
    Xs[e] = x[(size_t)(bz * 64 + ci) * 16384 + row * 128 + col];
  }
  __syncthreads();

  const int w = tid >> 6, co = tid & 63;
  const int par = w & 1;
  const int base = 8 * (w >> 1);

  int setcom;
  if (line == 0)      setcom = 8 | par;
  else if (line == 1) setcom = 12 | par;
  else if (line == 2) setcom = (par << 2) | 2;
  else                setcom = (par << 2) | 3;

  int uu[8];
  #pragma unroll
  for (int k = 0; k < 8; ++k) uu[k] = seg * 32 + 16 * (w >> 1) + 2 * k + par;

  float acc[8] = {0.f, 0.f, 0.f, 0.f, 0.f, 0.f, 0.f, 0.f};
  const float* Ecom = EdgeEff + setcom * 36864 + co;

  if (is01) fix_loop<1>(Ecom, Xs, base, acc);
  else      fix_loop<0>(Ecom, Xs, base, acc);

  if (is01 && seg == 0 && w == 0) {
    const float* Ecor = EdgeEff + ((line == 0) ? 10 : 14) * 36864 + co;
    acc[0] = corner_acc(Ecor, Xs, 1);
  }
  if (is01 && seg == 7 && w == 3) {
    const float* Ecor = EdgeEff + ((line == 0) ? 11 : 15) * 36864 + co;
    acc[7] = corner_acc(Ecor, Xs, 14);
  }

  #pragma unroll
  for (int k = 0; k < 8; ++k) {
    float v = fmaxf(fmaf(A1s[co], acc[k], C1s[co]), 0.f);
    float part[8];
    #pragma unroll
    for (int c2 = 0; c2 < 8; ++c2) part[c2] = w2s[c2 * 64 + co] * v;
    #pragma unroll
    for (int m = 1; m < 64; m <<= 1) {
      #pragma unroll
      for (int c2 = 0; c2 < 8; ++c2) part[c2] += __shfl_xor(part[c2], m, 64);
    }
    bool valid = is01 || (uu[k] >= 1 && uu[k] <= 254);
    if (co < 8 && valid) {
      float y = fmaf(s2s[co], part[co], sh2s[co]);
      float o = (y > 1.0f) ? y : 0.f;
      int R = (line == 0) ? 0 : (line == 1) ? 255 : uu[k];
      int C = (line == 2) ? 0 : (line == 3) ? 255 : uu[k];
      xf[((bz * 8 + co) * 256 + R) * 256 + C] = o;
    }
  }
}

// ---------------------------------------------------------------------------
// K3: fused window-sum + row-max + NMS scan + stable top-8 candidates.
// Per (plane, 32-row chunk): stage 40 xf rows, hsum -> ws -> rm in LDS with
// op order identical to the former k_sep/k_cand pair (rm rows outside
// [0,255] = -inf, matching k_cand's guards). ws/rm never touch global.
// ---------------------------------------------------------------------------
__global__ __launch_bounds__(256) void k_scan(const float* __restrict__ xf,
                                              float* __restrict__ candv,
                                              int* __restrict__ candi) {
  __shared__ float bufA[40 * 256];   // xf rows r0-4..r0+35, then ws rows (36)
  __shared__ float bufB[40 * 256];   // hsum rows (40), then rm rows (36)
  __shared__ float cv[256 * 8];
  __shared__ int cidx[256 * 8];
  const int t = threadIdx.x;
  const int plane = blockIdx.x >> 3;
  const int r0 = (blockIdx.x & 7) * 32;
  const float* xp = xf + plane * 65536;

  for (int i = t; i < 40 * 256; i += 256) {
    int rr = r0 - 4 + (i >> 8);
    bufA[i] = ((unsigned)rr < 256u) ? xp[(rr << 8) | (i & 255)] : 0.f;
  }
  __syncthreads();

  // horizontal 5-sum (same guarded order as k_sep)
  #pragma unroll 4
  for (int i = 0; i < 40; ++i) {
    const float* row = bufA + i * 256;
    float s = 0.f;
    #pragma unroll
    for (int d = -2; d <= 2; ++d) {
      int cc = t + d;
      if ((unsigned)cc < 256u) s += row[cc];
    }
    bufB[i * 256 + t] = s;
  }
  __syncthreads();

  // vertical 5-sum: ws row jj (global gr = r0-2+jj) into bufA (l-to-r order)
  #pragma unroll 4
  for (int jj = 0; jj < 36; ++jj) {
    float s = bufB[jj * 256 + t] + bufB[(jj + 1) * 256 + t] + bufB[(jj + 2) * 256 + t] +
              bufB[(jj + 3) * 256 + t] + bufB[(jj + 4) * 256 + t];
    bufA[jj * 256 + t] = s;
  }
  __syncthreads();

  // row-max: rm row jj into bufB; OOB global rows -> -inf (k_cand semantics)
  #pragma unroll 4
  for (int jj = 0; jj < 36; ++jj) {
    int gr = r0 - 2 + jj;
    float m = -HUGE_VALF;
    if ((unsigned)gr < 256u) {
      #pragma unroll
      for (int d = -2; d <= 2; ++d) {
        int cc = t + d;
        if ((unsigned)cc < 256u) m = fmaxf(m, bufA[jj * 256 + cc]);
      }
    }
    bufB[jj * 256 + t] = m;
  }
  __syncthreads();

  // NMS scan + thread-local top-8 (identical logic to k_cand)
  float bv[8]; int bi[8];
  #pragma unroll
  for (int k = 0; k < 8; ++k) { bv[k] = -HUGE_VALF; bi[k] = 0x7fffffff; }

  float w0 = bufB[0 * 256 + t];    // rm row r0-2 (already -inf if OOB)
  float w1v = bufB[1 * 256 + t];   // r0-1
  float w2v = bufB[2 * 256 + t];   // r0
  float w3v = bufB[3 * 256 + t];   // r0+1
  for (int r = r0; r < r0 + 32; ++r) {
    int jj = r - r0;
    float w4v = bufB[(jj + 4) * 256 + t];   // r+2
    float mp = fmaxf(fmaxf(fmaxf(w0, w1v), fmaxf(w2v, w3v)), w4v);
    float wsv = bufA[(jj + 2) * 256 + t];   // ws row r
    float mv = (wsv == mp) ? wsv : 0.f;
    int e = (r << 8) | t;
    if (better(mv, e, bv[7], bi[7])) {
      bv[7] = mv; bi[7] = e;
      #pragma unroll
      for (int k = 7; k > 0; --k) {
        if (better(bv[k], bi[k], bv[k - 1], bi[k - 1])) {
          float tv = bv[k]; bv[k] = bv[k - 1]; bv[k - 1] = tv;
          int ti = bi[k]; bi[k] = bi[k - 1]; bi[k - 1] = ti;
        }
      }
    }
    w0 = w1v; w1v = w2v; w2v = w3v; w3v = w4v;
  }

  #pragma unroll
  for (int k = 0; k < 8; ++k) { cv[t * 8 + k] = bv[k]; cidx[t * 8 + k] = bi[k]; }
  __syncthreads();

  for (int s = 128; s >= 1; s >>= 1) {
    if (t < s) {
      float ov[8]; int oi[8];
      int ia = 0, ib = 0;
      #pragma unroll
      for (int k = 0; k < 8; ++k) {
        float va = cv[t * 8 + ia];       int xa = cidx[t * 8 + ia];
        float vb = cv[(t + s) * 8 + ib]; int xb = cidx[(t + s) * 8 + ib];
        if (better(va, xa, vb, xb)) { ov[k] = va; oi[k] = xa; ++ia; }
        else                        { ov[k] = vb; oi[k] = xb; ++ib; }
      }
      #pragma unroll
      for (int k = 0; k < 8; ++k) { cv[t * 8 + k] = ov[k]; cidx[t * 8 + k] = oi[k]; }
    }
    __syncthreads();
  }

  if (t < 8) {
    candv[blockIdx.x * 8 + t] = cv[t];
    candi[blockIdx.x * 8 + t] = cidx[t];
  }
}

// ---------------------------------------------------------------------------
// K4: merge 8x8 candidates per plane, extract patches and positions.
// ---------------------------------------------------------------------------
__global__ __launch_bounds__(256) void k_final(const float* __restrict__ candv,
                                               const int* __restrict__ candi,
                                               const float* __restrict__ xf,
                                               float* __restrict__ patches,
                                               float* __restrict__ pos) {
  __shared__ float cvs[64];
  __shared__ int cis[64];
  __shared__ int fidx[8];
  const int t = threadIdx.x;
  const int plane = blockIdx.x;

  if (t < 64) { cvs[t] = candv[plane * 64 + t]; cis[t] = candi[plane * 64 + t]; }
  __syncthreads();
  if (t < 64) {
    float v = cvs[t]; int i = cis[t];
    int rank = 0;
    for (int m = 0; m < 64; ++m)
      if (better(cvs[m], cis[m], v, i)) ++rank;
    if (rank < 8) fidx[rank] = i;
  }
  __syncthreads();

  const float* xfp = xf + plane * 65536;
  if (t < 200) {
    int n = t / 25, e = t % 25;
    int kr = e / 5, kc = e % 5;
    int idx = fidx[n];
    int h = idx >> 8, w = idx & 255;
    int rr = h - 2 + kr, cc = w - 2 + kc;
    float v = ((unsigned)rr < 256u && (unsigned)cc < 256u) ? xfp[rr * 256 + cc] : 0.f;
    patches[plane * 200 + t] = v;
  } else if (t < 232) {
    int qq = t - 200;
    int n = qq >> 2, k = qq & 3;
    int idx = fidx[n];
    int h = idx >> 8, w = idx & 255;
    int val;
    if (k == 0)      val = min(max(w - 2, 0), 255);
    else if (k == 1) val = min(max(h - 2, 0), 255);
    else if (k == 2) val = min(max(w + 2, 0), 255);
    else             val = min(max(h + 2, 0), 255);
    pos[plane * 32 + qq] = (float)val;
  }
}

// ---------------------------------------------------------------------------
extern "C" void kernel_launch(void* const* d_in, const int* in_sizes, int n_in,
                              void* d_out, int out_size, void* d_ws, size_t ws_size,
                              hipStream_t stream) {
  (void)in_sizes; (void)n_in; (void)out_size; (void)ws_size;
  const float* x   = (const float*)d_in[0];
  const float* w1  = (const float*)d_in[1];
  const float* b1  = (const float*)d_in[2];
  const float* g1  = (const float*)d_in[3];
  const float* be1 = (const float*)d_in[4];
  const float* m1  = (const float*)d_in[5];
  const float* v1  = (const float*)d_in[6];
  const float* w2  = (const float*)d_in[7];
  const float* g2  = (const float*)d_in[8];
  const float* be2 = (const float*)d_in[9];
  const float* m2  = (const float*)d_in[10];
  const float* v2  = (const float*)d_in[11];

  float* out = (float*)d_out;
  const int PLANE = 8 * 8 * 256 * 256;   // 4,194,304
  float* xf   = (float*)d_ws;
  float* bufA = xf + PLANE;              // prep tables live here
  float* bufB = bufA + PLANE;            // (unused by k_scan; kept for layout)
  float* candv = bufB + PLANE;           // 4096 floats
  int*   candi = (int*)(candv + 4096);   // 4096 ints
  unsigned short* Wphase = (unsigned short*)bufA;   // 576 KB
  float* EdgeEff = bufA + 147456;                   // 2.25 MB

  k_wprep<<<2880, 256, 0, stream>>>(w1, Wphase, EdgeEff);
  k_front<<<dim3(16, 16, 4), 512, 0, stream>>>(x, Wphase, b1, g1, be1, m1, v1,
                                               w2, g2, be2, m2, v2, xf);
  k_fix<<<dim3(8, 4, 8), 256, 0, stream>>>(x, EdgeEff, b1, g1, be1, m1, v1,
                                           w2, g2, be2, m2, v2, xf);
  k_scan<<<512, 256, 0, stream>>>(xf, candv, candi);
  k_final<<<64, 256, 0, stream>>>(candv, candi, xf, out, out + 12800);
}

// Round 11
// 344.977 us; speedup vs baseline: 1.0861x; 1.0861x over previous
//
#include <hip/hip_runtime.h>
#include <math.h>

#define EPS 1e-5f

typedef __attribute__((ext_vector_type(8))) short short8;
typedef __attribute__((ext_vector_type(4))) float float4v;

__device__ __forceinline__ bool better(float v1, int i1, float v2, int i2) {
  return (v1 > v2) || (v1 == v2 && i1 < i2);
}

__device__ __forceinline__ unsigned short f2bf(float f) {
  unsigned int u = __float_as_uint(f);
  unsigned int r = u + 0x7fffu + ((u >> 16) & 1u);
  return (unsigned short)(r >> 16);
}
__device__ __forceinline__ float bf2f(unsigned short s) {
  return __uint_as_float(((unsigned int)s) << 16);
}

// Row-coefficient table: RCtab[situation][kr][dr]
// situation: 0 = even phase (R=2i), 1 = odd phase (R=2i+1),
//            2 = lo edge (R=0, base row 0), 3 = hi edge (R=255, base row 125)
__device__ __constant__ float RCtab[4][3][3] = {
  {{0.75f, 0.25f, 0.f}, {0.25f, 0.75f, 0.f}, {0.f, 0.75f, 0.25f}},
  {{0.25f, 0.75f, 0.f}, {0.f, 0.75f, 0.25f}, {0.f, 0.25f, 0.75f}},
  {{0.f, 0.f, 0.f},     {1.0f, 0.f, 0.f},    {0.75f, 0.25f, 0.f}},
  {{0.f, 0.25f, 0.75f}, {0.f, 0.f, 1.0f},    {0.f, 0.f, 0.f}},
};

// ---------------------------------------------------------------------------
// K0: precompute (a) 4 interior phase filters as bf16 hi/lo for MFMA B-frags,
//     (b) 16 (row-sit x col-sit) fp32 filter sets for the border fixup.
// ---------------------------------------------------------------------------
__global__ __launch_bounds__(256) void k_wprep(const float* __restrict__ w1,
                                               unsigned short* __restrict__ Wphase,
                                               float* __restrict__ EdgeEff) {
  int e = blockIdx.x * 256 + threadIdx.x;
  if (e < 147456) {
    int cil = e & 31, co = (e >> 5) & 63, ck = (e >> 11) & 1;
    int tap = (e >> 12) % 9, ph = e / 36864;     // ph = pr*2+pc
    int pr = ph >> 1, pc = ph & 1;
    int dr = tap / 3, dc = tap % 3;
    int ci = ck * 32 + cil;
    const float* wp = w1 + (co * 64 + ci) * 9;
    float eff = 0.f;
    #pragma unroll
    for (int kr = 0; kr < 3; ++kr)
      #pragma unroll
      for (int kc = 0; kc < 3; ++kc)
        eff += wp[kr * 3 + kc] * RCtab[pr][kr][dr] * RCtab[pc][kc][dc];
    unsigned short hi = f2bf(eff);
    unsigned short lo = f2bf(eff - bf2f(hi));
    int g = (ph * 9 + tap) * 2 + ck;
    Wphase[g * 4096 + co * 32 + cil] = hi;
    Wphase[g * 4096 + 2048 + co * 32 + cil] = lo;
  } else if (e < 147456 + 589824) {
    int e2 = e - 147456;
    int co = e2 & 63, tap = (e2 >> 6) % 9, ci = (e2 / 576) & 63, set = e2 / 36864;
    int rs = set >> 2, cs = set & 3;
    int dr = tap / 3, dc = tap % 3;
    const float* wp = w1 + (co * 64 + ci) * 9;
    float eff = 0.f;
    #pragma unroll
    for (int kr = 0; kr < 3; ++kr)
      #pragma unroll
      for (int kc = 0; kc < 3; ++kc)
        eff += wp[kr * 3 + kc] * RCtab[rs][kr][dr] * RCtab[cs][kc][dc];
    EdgeEff[set * 36864 + (ci * 9 + tap) * 64 + co] = eff;
  }
}

// ---------------------------------------------------------------------------
// K1: conv(upsample) via 4 phase filters (proven R9 256-thread version;
// R10's 512-thread split regressed — occupancy is not the binding constraint).
// launch_bounds (256,1): ~360 regs/wave, no spill.
// ---------------------------------------------------------------------------
__global__ __launch_bounds__(256, 1) void k_front(
    const float* __restrict__ x, const unsigned short* __restrict__ Wphase,
    const float* __restrict__ b1, const float* __restrict__ g1,
    const float* __restrict__ be1, const float* __restrict__ m1,
    const float* __restrict__ v1, const float* __restrict__ w2,
    const float* __restrict__ g2, const float* __restrict__ be2,
    const float* __restrict__ m2, const float* __restrict__ v2,
    float* __restrict__ xf)
{
  // 8 staging buffers [b][ck][hl] of 100 pos x 40 shorts = 64000 B,
  // aliased by epilogue V fp32 256x65 = 66560 B.
  __shared__ __align__(16) char lds[66560];
  unsigned short* XS = (unsigned short*)lds;
  float* V = (float*)lds;
  __shared__ float w2s[512];
  __shared__ float A1s[64], C1s[64];
  __shared__ float s2s[8], sh2s[8];

  const int tid = threadIdx.x;
  const int bx = blockIdx.x, by = blockIdx.y, bz = blockIdx.z;

  for (int i = tid; i < 512; i += 256) w2s[i] = w2[i];
  if (tid < 64) {
    float sc = g1[tid] * rsqrtf(v1[tid] + EPS);
    A1s[tid] = sc;
    C1s[tid] = sc * (b1[tid] - m1[tid]) + be1[tid];
  }
  if (tid < 8) {
    float sc = g2[tid] * rsqrtf(v2[tid] + EPS);
    s2s[tid] = sc;
    sh2s[tid] = be2[tid] - m2[tid] * sc;
  }

  // --- stage clamped 10x10 x-tile, 64 ci, hi/lo, both batches ---
  if (tid < 200) {
    int ckh = tid / 100;
    int pos = tid % 100;
    int r = pos / 10, c = pos % 10;
    int rr = min(max(by * 8 - 1 + r, 0), 127);
    int cc = min(max(bx * 8 - 1 + c, 0), 127);
    #pragma unroll
    for (int b = 0; b < 2; ++b) {
      const float* xp = x + (size_t)((bz * 2 + b) * 64 + ckh * 32) * 16384 + rr * 128 + cc;
      unsigned int* dh = (unsigned int*)(XS + ((b * 2 + ckh) * 2 + 0) * 4000) + pos * 20;
      unsigned int* dl = (unsigned int*)(XS + ((b * 2 + ckh) * 2 + 1) * 4000) + pos * 20;
      for (int cp = 0; cp < 16; ++cp) {
        float v0 = xp[(size_t)(2 * cp) * 16384];
        float v1x = xp[(size_t)(2 * cp + 1) * 16384];
        unsigned short h0 = f2bf(v0), h1 = f2bf(v1x);
        unsigned short l0 = f2bf(v0 - bf2f(h0)), l1 = f2bf(v1x - bf2f(h1));
        dh[cp] = (unsigned int)h0 | ((unsigned int)h1 << 16);
        dl[cp] = (unsigned int)l0 | ((unsigned int)l1 << 16);
      }
    }
  }
  __syncthreads();

  const int l = tid & 63, wv = tid >> 6;     // wv = phase = pr*2+pc
  const int pr = wv >> 1, pc = wv & 1;
  const int lm = l & 15, q = l >> 4;
  const int arow = lm >> 3, acol = lm & 7;

  float4v acc[2][4][4];
  #pragma unroll
  for (int b = 0; b < 2; ++b)
    #pragma unroll
    for (int mt = 0; mt < 4; ++mt)
      #pragma unroll
      for (int nt = 0; nt < 4; ++nt) acc[b][mt][nt] = (float4v){0.f, 0.f, 0.f, 0.f};

  #pragma unroll
  for (int ck = 0; ck < 2; ++ck) {
    #pragma unroll
    for (int tap = 0; tap < 9; ++tap) {
      const int dr = tap / 3, dc = tap % 3;
      const unsigned short* wb = Wphase + ((wv * 9 + tap) * 2 + ck) * 4096;
      short8 bh[4], bl[4];
      #pragma unroll
      for (int nt = 0; nt < 4; ++nt) {
        int off = (nt * 16 + lm) * 32 + q * 8;
        bh[nt] = *(const short8*)(wb + off);
        bl[nt] = *(const short8*)(wb + 2048 + off);
      }
      #pragma unroll
      for (int b = 0; b < 2; ++b) {
        const unsigned short* XH = XS + ((b * 2 + ck) * 2 + 0) * 4000;
        const unsigned short* XL = XS + ((b * 2 + ck) * 2 + 1) * 4000;
        #pragma unroll
        for (int mt = 0; mt < 4; ++mt) {
          int pos = (mt * 2 + arow + dr) * 10 + acol + dc;
          short8 ah = *(const short8*)(XH + pos * 40 + q * 8);
          short8 al = *(const short8*)(XL + pos * 40 + q * 8);
          #pragma unroll
          for (int nt = 0; nt < 4; ++nt) {
            acc[b][mt][nt] = __builtin_amdgcn_mfma_f32_16x16x32_bf16(ah, bh[nt], acc[b][mt][nt], 0, 0, 0);
            acc[b][mt][nt] = __builtin_amdgcn_mfma_f32_16x16x32_bf16(al, bh[nt], acc[b][mt][nt], 0, 0, 0);
            acc[b][mt][nt] = __builtin_amdgcn_mfma_f32_16x16x32_bf16(ah, bl[nt], acc[b][mt][nt], 0, 0, 0);
          }
        }
      }
    }
  }

  // --- epilogue per batch: acc -> V (BN1+ReLU) -> fp32 1x1 + BN2 + filter ---
  #pragma unroll
  for (int b = 0; b < 2; ++b) {
    __syncthreads();   // staging (b=0) or previous V reads (b=1) complete
    #pragma unroll
    for (int mt = 0; mt < 4; ++mt) {
      #pragma unroll
      for (int nt = 0; nt < 4; ++nt) {
        int co = nt * 16 + lm;
        float A = A1s[co], Cc = C1s[co];
        #pragma unroll
        for (int r = 0; r < 4; ++r) {
          int p = mt * 16 + q * 4 + r;               // pixel within phase (8x8)
          int ur = 2 * (p >> 3) + pr, uc = 2 * (p & 7) + pc;
          V[(ur * 16 + uc) * 65 + co] = fmaxf(fmaf(A, acc[b][mt][nt][r], Cc), 0.f);
        }
      }
    }
    __syncthreads();
    {
      float a2[8];
      #pragma unroll
      for (int c2 = 0; c2 < 8; ++c2) a2[c2] = 0.f;
      const float* vp = &V[tid * 65];
      for (int co = 0; co < 64; ++co) {
        float xv = vp[co];
        #pragma unroll
        for (int c2 = 0; c2 < 8; ++c2) a2[c2] = fmaf(w2s[c2 * 64 + co], xv, a2[c2]);
      }
      int ur = tid >> 4, uc = tid & 15;
      int batch = bz * 2 + b;
      #pragma unroll
      for (int c2 = 0; c2 < 8; ++c2) {
        float y = fmaf(s2s[c2], a2[c2], sh2s[c2]);
        float o = (y > 1.0f) ? y : 0.f;
        xf[((batch * 8 + c2) * 256 + by * 16 + ur) * 256 + bx * 16 + uc] = o;
      }
    }
  }
}

// ---------------------------------------------------------------------------
// k_fix v3 helpers (proven R9).
// ---------------------------------------------------------------------------
template<int S_IS_DR>
__device__ __forceinline__ void fix_loop(const float* __restrict__ Ecom,
                                         const float* __restrict__ Xs,
                                         int base, float acc[8]) {
  for (int ci = 0; ci < 64; ++ci) {
    const float* xsrow = Xs + ci * 60;
    float run0[12], run1[12], run2[12];
    #pragma unroll
    for (int j = 0; j < 3; ++j) {
      ((float4*)run0)[j] = ((const float4*)(xsrow + base))[j];
      ((float4*)run1)[j] = ((const float4*)(xsrow + 20 + base))[j];
      ((float4*)run2)[j] = ((const float4*)(xsrow + 40 + base))[j];
    }
    float wt[9];
    #pragma unroll
    for (int tap = 0; tap < 9; ++tap) wt[tap] = Ecom[(ci * 9 + tap) * 64];
    #pragma unroll
    for (int tap = 0; tap < 9; ++tap) {
      const int dr = tap / 3, dc = tap % 3;
      const int s = S_IS_DR ? dr : dc;
      const int d = S_IS_DR ? dc : dr;
      const float* run = (s == 0) ? run0 : ((s == 1) ? run1 : run2);
      #pragma unroll
      for (int k = 0; k < 8; ++k)
        acc[k] = fmaf(wt[tap], run[k + d], acc[k]);
    }
  }
}

__device__ __forceinline__ float corner_acc(const float* __restrict__ Ecor,
                                            const float* __restrict__ Xs,
                                            int pcor) {
  float a = 0.f;
  for (int ci = 0; ci < 64; ++ci) {
    const float* xsrow = Xs + ci * 60;
    #pragma unroll
    for (int tap = 0; tap < 9; ++tap) {
      const int dr = tap / 3, dc = tap % 3;
      a = fmaf(Ecor[(ci * 9 + tap) * 64], xsrow[dr * 20 + pcor + dc], a);
    }
  }
  return a;
}

// ---------------------------------------------------------------------------
// K2: border fixup v3 (proven R9).
// ---------------------------------------------------------------------------
__global__ __launch_bounds__(256, 1) void k_fix(
    const float* __restrict__ x, const float* __restrict__ EdgeEff,
    const float* __restrict__ b1, const float* __restrict__ g1,
    const float* __restrict__ be1, const float* __restrict__ m1,
    const float* __restrict__ v1, const float* __restrict__ w2,
    const float* __restrict__ g2, const float* __restrict__ be2,
    const float* __restrict__ m2, const float* __restrict__ v2,
    float* __restrict__ xf)
{
  __shared__ __align__(16) float Xs[64 * 60];   // [ci][slot3][fast20]
  __shared__ float w2s[512];
  __shared__ float A1s[64], C1s[64];
  __shared__ float s2s[8], sh2s[8];

  const int tid = threadIdx.x;
  const int seg = blockIdx.x, line = blockIdx.y, bz = blockIdx.z;
  const bool is01 = (line < 2);

  for (int i = tid; i < 512; i += 256) w2s[i] = w2[i];
  if (tid < 64) {
    float sc = g1[tid] * rsqrtf(v1[tid] + EPS);
    A1s[tid] = sc;
    C1s[tid] = sc * (b1[tid] - m1[tid]) + be1[tid];
  }
  if (tid < 8) {
    float sc = g2[tid] * rsqrtf(v2[tid] + EPS);
    s2s[tid] = sc;
    sh2s[tid] = be2[tid] - m2[tid] * sc;
  }

  const int base0 = seg * 16 - 1;
  for (int e = tid; e < 3840; e += 256) {
    int f = e % 20;
    int slot = (e / 20) % 3;
    int ci = e / 60;
    int row, col;
    if (is01) { row = (line == 0 ? 0 : 125) + slot; col = min(max(base0 + f, 0), 127); }
    else      { col = (line == 2 ? 0 : 125) + slot; row = min(max(base0 + f, 0), 127); }
    Xs[e] = x[(size_t)(bz * 64 + ci) * 16384 + row * 128 + col];
  }
  __syncthreads();

  const int w = tid >> 6, co = tid & 63;
  const int par = w & 1;
  const int base = 8 * (w >> 1);

  int setcom;
  if (line == 0)      setcom = 8 | par;
  else if (line == 1) setcom = 12 | par;
  else if (line == 2) setcom = (par << 2) | 2;
  else                setcom = (par << 2) | 3;

  int uu[8];
  #pragma unroll
  for (int k = 0; k < 8; ++k) uu[k] = seg * 32 + 16 * (w >> 1) + 2 * k + par;

  float acc[8] = {0.f, 0.f, 0.f, 0.f, 0.f, 0.f, 0.f, 0.f};
  const float* Ecom = EdgeEff + setcom * 36864 + co;

  if (is01) fix_loop<1>(Ecom, Xs, base, acc);
  else      fix_loop<0>(Ecom, Xs, base, acc);

  if (is01 && seg == 0 && w == 0) {
    const float* Ecor = EdgeEff + ((line == 0) ? 10 : 14) * 36864 + co;
    acc[0] = corner_acc(Ecor, Xs, 1);
  }
  if (is01 && seg == 7 && w == 3) {
    const float* Ecor = EdgeEff + ((line == 0) ? 11 : 15) * 36864 + co;
    acc[7] = corner_acc(Ecor, Xs, 14);
  }

  #pragma unroll
  for (int k = 0; k < 8; ++k) {
    float v = fmaxf(fmaf(A1s[co], acc[k], C1s[co]), 0.f);
    float part[8];
    #pragma unroll
    for (int c2 = 0; c2 < 8; ++c2) part[c2] = w2s[c2 * 64 + co] * v;
    #pragma unroll
    for (int m = 1; m < 64; m <<= 1) {
      #pragma unroll
      for (int c2 = 0; c2 < 8; ++c2) part[c2] += __shfl_xor(part[c2], m, 64);
    }
    bool valid = is01 || (uu[k] >= 1 && uu[k] <= 254);
    if (co < 8 && valid) {
      float y = fmaf(s2s[co], part[co], sh2s[co]);
      float o = (y > 1.0f) ? y : 0.f;
      int R = (line == 0) ? 0 : (line == 1) ? 255 : uu[k];
      int C = (line == 2) ? 0 : (line == 3) ? 255 : uu[k];
      xf[((bz * 8 + co) * 256 + R) * 256 + C] = o;
    }
  }
}

// ---------------------------------------------------------------------------
// K3: separable 5x5 window-sum + local row-max + NMS mask, emitting masked
// ws (mv) directly. rm rows r0-2..r0+17 are computed locally — bitwise equal
// to the neighbor-chunk values (same xf, same op order). All fmaxf/add
// chains replicate the former k_sep/k_cand pair exactly.
// ---------------------------------------------------------------------------
__global__ __launch_bounds__(256) void k_sep(const float* __restrict__ xf,
                                             float* __restrict__ mv) {
  __shared__ float A[24 * 256];
  __shared__ float B[24 * 256];
  const int plane = blockIdx.x >> 4;
  const int r0 = (blockIdx.x & 15) * 16;
  const int t = threadIdx.x;
  const float* xp = xf + plane * 65536;

  // stage xf rows r0-4 .. r0+19 (zero outside)
  for (int i = t; i < 24 * 256; i += 256) {
    int rr = r0 - 4 + (i >> 8);
    A[i] = ((unsigned)rr < 256u) ? xp[(rr << 8) | (i & 255)] : 0.f;
  }
  __syncthreads();

  // horizontal 5-sum (guarded, d ascending) -> B
  #pragma unroll 4
  for (int i = 0; i < 24; ++i) {
    const float* row = A + i * 256;
    float s = 0.f;
    #pragma unroll
    for (int d = -2; d <= 2; ++d) {
      int cc = t + d;
      if ((unsigned)cc < 256u) s += row[cc];
    }
    B[i * 256 + t] = s;
  }
  __syncthreads();

  // vertical 5-sum: ws row g=r0-2+k -> A slot k (left-to-right)
  #pragma unroll 4
  for (int k = 0; k < 20; ++k) {
    float s = B[k * 256 + t] + B[(k + 1) * 256 + t] + B[(k + 2) * 256 + t] +
              B[(k + 3) * 256 + t] + B[(k + 4) * 256 + t];
    A[k * 256 + t] = s;
  }
  __syncthreads();

  // row-max: rm row g=r0-2+k -> B slot k; OOB global rows -> -inf
  #pragma unroll 4
  for (int k = 0; k < 20; ++k) {
    int g = r0 - 2 + k;
    float m = -HUGE_VALF;
    if ((unsigned)g < 256u) {
      #pragma unroll
      for (int d = -2; d <= 2; ++d) {
        int cc = t + d;
        if ((unsigned)cc < 256u) m = fmaxf(m, A[k * 256 + cc]);
      }
    }
    B[k * 256 + t] = m;
  }
  __syncthreads();

  // mp over rm rows r-2..r+2 (same fmaxf tree as the old k_cand), mask, emit
  #pragma unroll 4
  for (int i = 0; i < 16; ++i) {
    float w0 = B[i * 256 + t], w1v = B[(i + 1) * 256 + t];
    float w2v = B[(i + 2) * 256 + t], w3v = B[(i + 3) * 256 + t];
    float w4v = B[(i + 4) * 256 + t];
    float mp = fmaxf(fmaxf(fmaxf(w0, w1v), fmaxf(w2v, w3v)), w4v);
    float wsv = A[(i + 2) * 256 + t];
    mv[plane * 65536 + (r0 + i) * 256 + t] = (wsv == mp) ? wsv : 0.f;
  }
}

// ---------------------------------------------------------------------------
// K4: streaming stable top-8 over masked values (selection order identical
// to the former k_cand: value desc, index asc, e=(r<<8)|t).
// ---------------------------------------------------------------------------
__global__ __launch_bounds__(256) void k_cand(const float* __restrict__ mv,
                                              float* __restrict__ candv,
                                              int* __restrict__ candi) {
  __shared__ float cv[256 * 8];
  __shared__ int cidx[256 * 8];
  const int t = threadIdx.x;
  const int plane = blockIdx.x >> 3;
  const int r0 = (blockIdx.x & 7) * 32;
  const float* mvp = mv + plane * 65536;

  float bv[8]; int bi[8];
  #pragma unroll
  for (int k = 0; k < 8; ++k) { bv[k] = -HUGE_VALF; bi[k] = 0x7fffffff; }

  for (int r = r0; r < r0 + 32; ++r) {
    float m = mvp[r * 256 + t];
    int e = (r << 8) | t;
    if (better(m, e, bv[7], bi[7])) {
      bv[7] = m; bi[7] = e;
      #pragma unroll
      for (int k = 7; k > 0; --k) {
        if (better(bv[k], bi[k], bv[k - 1], bi[k - 1])) {
          float tv = bv[k]; bv[k] = bv[k - 1]; bv[k - 1] = tv;
          int ti = bi[k]; bi[k] = bi[k - 1]; bi[k - 1] = ti;
        }
      }
    }
  }

  #pragma unroll
  for (int k = 0; k < 8; ++k) { cv[t * 8 + k] = bv[k]; cidx[t * 8 + k] = bi[k]; }
  __syncthreads();

  for (int s = 128; s >= 1; s >>= 1) {
    if (t < s) {
      float ov[8]; int oi[8];
      int ia = 0, ib = 0;
      #pragma unroll
      for (int k = 0; k < 8; ++k) {
        float va = cv[t * 8 + ia];       int xa = cidx[t * 8 + ia];
        float vb = cv[(t + s) * 8 + ib]; int xb = cidx[(t + s) * 8 + ib];
        if (better(va, xa, vb, xb)) { ov[k] = va; oi[k] = xa; ++ia; }
        else                        { ov[k] = vb; oi[k] = xb; ++ib; }
      }
      #pragma unroll
      for (int k = 0; k < 8; ++k) { cv[t * 8 + k] = ov[k]; cidx[t * 8 + k] = oi[k]; }
    }
    __syncthreads();
  }

  if (t < 8) {
    candv[blockIdx.x * 8 + t] = cv[t];
    candi[blockIdx.x * 8 + t] = cidx[t];
  }
}

// ---------------------------------------------------------------------------
// K5: merge 8x8 candidates per plane, extract patches and positions.
// ---------------------------------------------------------------------------
__global__ __launch_bounds__(256) void k_final(const float* __restrict__ candv,
                                               const int* __restrict__ candi,
                                               const float* __restrict__ xf,
                                               float* __restrict__ patches,
                                               float* __restrict__ pos) {
  __shared__ float cvs[64];
  __shared__ int cis[64];
  __shared__ int fidx[8];
  const int t = threadIdx.x;
  const int plane = blockIdx.x;

  if (t < 64) { cvs[t] = candv[plane * 64 + t]; cis[t] = candi[plane * 64 + t]; }
  __syncthreads();
  if (t < 64) {
    float v = cvs[t]; int i = cis[t];
    int rank = 0;
    for (int m = 0; m < 64; ++m)
      if (better(cvs[m], cis[m], v, i)) ++rank;
    if (rank < 8) fidx[rank] = i;
  }
  __syncthreads();

  const float* xfp = xf + plane * 65536;
  if (t < 200) {
    int n = t / 25, e = t % 25;
    int kr = e / 5, kc = e % 5;
    int idx = fidx[n];
    int h = idx >> 8, w = idx & 255;
    int rr = h - 2 + kr, cc = w - 2 + kc;
    float v = ((unsigned)rr < 256u && (unsigned)cc < 256u) ? xfp[rr * 256 + cc] : 0.f;
    patches[plane * 200 + t] = v;
  } else if (t < 232) {
    int qq = t - 200;
    int n = qq >> 2, k = qq & 3;
    int idx = fidx[n];
    int h = idx >> 8, w = idx & 255;
    int val;
    if (k == 0)      val = min(max(w - 2, 0), 255);
    else if (k == 1) val = min(max(h - 2, 0), 255);
    else if (k == 2) val = min(max(w + 2, 0), 255);
    else             val = min(max(h + 2, 0), 255);
    pos[plane * 32 + qq] = (float)val;
  }
}

// ---------------------------------------------------------------------------
extern "C" void kernel_launch(void* const* d_in, const int* in_sizes, int n_in,
                              void* d_out, int out_size, void* d_ws, size_t ws_size,
                              hipStream_t stream) {
  (void)in_sizes; (void)n_in; (void)out_size; (void)ws_size;
  const float* x   = (const float*)d_in[0];
  const float* w1  = (const float*)d_in[1];
  const float* b1  = (const float*)d_in[2];
  const float* g1  = (const float*)d_in[3];
  const float* be1 = (const float*)d_in[4];
  const float* m1  = (const float*)d_in[5];
  const float* v1  = (const float*)d_in[6];
  const float* w2  = (const float*)d_in[7];
  const float* g2  = (const float*)d_in[8];
  const float* be2 = (const float*)d_in[9];
  const float* m2  = (const float*)d_in[10];
  const float* v2  = (const float*)d_in[11];

  float* out = (float*)d_out;
  const int PLANE = 8 * 8 * 256 * 256;   // 4,194,304
  float* xf   = (float*)d_ws;
  float* bufA = xf + PLANE;              // prep tables live here
  float* bufB = bufA + PLANE;            // masked window sums (mv)
  float* candv = bufB + PLANE;           // 4096 floats
  int*   candi = (int*)(candv + 4096);   // 4096 ints
  unsigned short* Wphase = (unsigned short*)bufA;   // 576 KB
  float* EdgeEff = bufA + 147456;                   // 2.25 MB

  k_wprep<<<2880, 256, 0, stream>>>(w1, Wphase, EdgeEff);
  k_front<<<dim3(16, 16, 4), 256, 0, stream>>>(x, Wphase, b1, g1, be1, m1, v1,
                                               w2, g2, be2, m2, v2, xf);
  k_fix<<<dim3(8, 4, 8), 256, 0, stream>>>(x, EdgeEff, b1, g1, be1, m1, v1,
                                           w2, g2, be2, m2, v2, xf);
  k_sep<<<1024, 256, 0, stream>>>(xf, bufB);
  k_cand<<<512, 256, 0, stream>>>(bufB, candv, candi);
  k_final<<<64, 256, 0, stream>>>(candv, candi, xf, out, out + 12800);
}

// Round 12
// 326.723 us; speedup vs baseline: 1.1468x; 1.0559x over previous
//
#include <hip/hip_runtime.h>
#include <math.h>

#define EPS 1e-5f

typedef __attribute__((ext_vector_type(8))) short short8;
typedef __attribute__((ext_vector_type(4))) float float4v;

__device__ __forceinline__ bool better(float v1, int i1, float v2, int i2) {
  return (v1 > v2) || (v1 == v2 && i1 < i2);
}

__device__ __forceinline__ unsigned short f2bf(float f) {
  unsigned int u = __float_as_uint(f);
  unsigned int r = u + 0x7fffu + ((u >> 16) & 1u);
  return (unsigned short)(r >> 16);
}
__device__ __forceinline__ float bf2f(unsigned short s) {
  return __uint_as_float(((unsigned int)s) << 16);
}

// Row-coefficient table: RCtab[situation][kr][dr]
// situation: 0 = even phase (R=2i), 1 = odd phase (R=2i+1),
//            2 = lo edge (R=0, base row 0), 3 = hi edge (R=255, base row 125)
__device__ __constant__ float RCtab[4][3][3] = {
  {{0.75f, 0.25f, 0.f}, {0.25f, 0.75f, 0.f}, {0.f, 0.75f, 0.25f}},
  {{0.25f, 0.75f, 0.f}, {0.f, 0.75f, 0.25f}, {0.f, 0.25f, 0.75f}},
  {{0.f, 0.f, 0.f},     {1.0f, 0.f, 0.f},    {0.75f, 0.25f, 0.f}},
  {{0.f, 0.25f, 0.75f}, {0.f, 0.f, 1.0f},    {0.f, 0.f, 0.f}},
};

// ---------------------------------------------------------------------------
// K0: precompute (a) 4 interior phase filters as bf16 hi/lo for MFMA B-frags,
//     (b) 16 (row-sit x col-sit) fp32 filter sets for the border fixup.
// ---------------------------------------------------------------------------
__global__ __launch_bounds__(256) void k_wprep(const float* __restrict__ w1,
                                               unsigned short* __restrict__ Wphase,
                                               float* __restrict__ EdgeEff) {
  int e = blockIdx.x * 256 + threadIdx.x;
  if (e < 147456) {
    int cil = e & 31, co = (e >> 5) & 63, ck = (e >> 11) & 1;
    int tap = (e >> 12) % 9, ph = e / 36864;     // ph = pr*2+pc
    int pr = ph >> 1, pc = ph & 1;
    int dr = tap / 3, dc = tap % 3;
    int ci = ck * 32 + cil;
    const float* wp = w1 + (co * 64 + ci) * 9;
    float eff = 0.f;
    #pragma unroll
    for (int kr = 0; kr < 3; ++kr)
      #pragma unroll
      for (int kc = 0; kc < 3; ++kc)
        eff += wp[kr * 3 + kc] * RCtab[pr][kr][dr] * RCtab[pc][kc][dc];
    unsigned short hi = f2bf(eff);
    unsigned short lo = f2bf(eff - bf2f(hi));
    int g = (ph * 9 + tap) * 2 + ck;
    Wphase[g * 4096 + co * 32 + cil] = hi;
    Wphase[g * 4096 + 2048 + co * 32 + cil] = lo;
  } else if (e < 147456 + 589824) {
    int e2 = e - 147456;
    int co = e2 & 63, tap = (e2 >> 6) % 9, ci = (e2 / 576) & 63, set = e2 / 36864;
    int rs = set >> 2, cs = set & 3;
    int dr = tap / 3, dc = tap % 3;
    const float* wp = w1 + (co * 64 + ci) * 9;
    float eff = 0.f;
    #pragma unroll
    for (int kr = 0; kr < 3; ++kr)
      #pragma unroll
      for (int kc = 0; kc < 3; ++kc)
        eff += wp[kr * 3 + kc] * RCtab[rs][kr][dr] * RCtab[cs][kc][dc];
    EdgeEff[set * 36864 + (ci * 9 + tap) * 64 + co] = eff;
  }
}

// ---------------------------------------------------------------------------
// K1: conv(upsample) via 4 phase filters (proven R9 256-thread version).
// launch_bounds (256,1): ~360 regs/wave, no spill. Do not restructure
// without bisection (R5/R10 regressions).
// ---------------------------------------------------------------------------
__global__ __launch_bounds__(256, 1) void k_front(
    const float* __restrict__ x, const unsigned short* __restrict__ Wphase,
    const float* __restrict__ b1, const float* __restrict__ g1,
    const float* __restrict__ be1, const float* __restrict__ m1,
    const float* __restrict__ v1, const float* __restrict__ w2,
    const float* __restrict__ g2, const float* __restrict__ be2,
    const float* __restrict__ m2, const float* __restrict__ v2,
    float* __restrict__ xf)
{
  // 8 staging buffers [b][ck][hl] of 100 pos x 40 shorts = 64000 B,
  // aliased by epilogue V fp32 256x65 = 66560 B.
  __shared__ __align__(16) char lds[66560];
  unsigned short* XS = (unsigned short*)lds;
  float* V = (float*)lds;
  __shared__ float w2s[512];
  __shared__ float A1s[64], C1s[64];
  __shared__ float s2s[8], sh2s[8];

  const int tid = threadIdx.x;
  const int bx = blockIdx.x, by = blockIdx.y, bz = blockIdx.z;

  for (int i = tid; i < 512; i += 256) w2s[i] = w2[i];
  if (tid < 64) {
    float sc = g1[tid] * rsqrtf(v1[tid] + EPS);
    A1s[tid] = sc;
    C1s[tid] = sc * (b1[tid] - m1[tid]) + be1[tid];
  }
  if (tid < 8) {
    float sc = g2[tid] * rsqrtf(v2[tid] + EPS);
    s2s[tid] = sc;
    sh2s[tid] = be2[tid] - m2[tid] * sc;
  }

  // --- stage clamped 10x10 x-tile, 64 ci, hi/lo, both batches ---
  if (tid < 200) {
    int ckh = tid / 100;
    int pos = tid % 100;
    int r = pos / 10, c = pos % 10;
    int rr = min(max(by * 8 - 1 + r, 0), 127);
    int cc = min(max(bx * 8 - 1 + c, 0), 127);
    #pragma unroll
    for (int b = 0; b < 2; ++b) {
      const float* xp = x + (size_t)((bz * 2 + b) * 64 + ckh * 32) * 16384 + rr * 128 + cc;
      unsigned int* dh = (unsigned int*)(XS + ((b * 2 + ckh) * 2 + 0) * 4000) + pos * 20;
      unsigned int* dl = (unsigned int*)(XS + ((b * 2 + ckh) * 2 + 1) * 4000) + pos * 20;
      for (int cp = 0; cp < 16; ++cp) {
        float v0 = xp[(size_t)(2 * cp) * 16384];
        float v1x = xp[(size_t)(2 * cp + 1) * 16384];
        unsigned short h0 = f2bf(v0), h1 = f2bf(v1x);
        unsigned short l0 = f2bf(v0 - bf2f(h0)), l1 = f2bf(v1x - bf2f(h1));
        dh[cp] = (unsigned int)h0 | ((unsigned int)h1 << 16);
        dl[cp] = (unsigned int)l0 | ((unsigned int)l1 << 16);
      }
    }
  }
  __syncthreads();

  const int l = tid & 63, wv = tid >> 6;     // wv = phase = pr*2+pc
  const int pr = wv >> 1, pc = wv & 1;
  const int lm = l & 15, q = l >> 4;
  const int arow = lm >> 3, acol = lm & 7;

  float4v acc[2][4][4];
  #pragma unroll
  for (int b = 0; b < 2; ++b)
    #pragma unroll
    for (int mt = 0; mt < 4; ++mt)
      #pragma unroll
      for (int nt = 0; nt < 4; ++nt) acc[b][mt][nt] = (float4v){0.f, 0.f, 0.f, 0.f};

  #pragma unroll
  for (int ck = 0; ck < 2; ++ck) {
    #pragma unroll
    for (int tap = 0; tap < 9; ++tap) {
      const int dr = tap / 3, dc = tap % 3;
      const unsigned short* wb = Wphase + ((wv * 9 + tap) * 2 + ck) * 4096;
      short8 bh[4], bl[4];
      #pragma unroll
      for (int nt = 0; nt < 4; ++nt) {
        int off = (nt * 16 + lm) * 32 + q * 8;
        bh[nt] = *(const short8*)(wb + off);
        bl[nt] = *(const short8*)(wb + 2048 + off);
      }
      #pragma unroll
      for (int b = 0; b < 2; ++b) {
        const unsigned short* XH = XS + ((b * 2 + ck) * 2 + 0) * 4000;
        const unsigned short* XL = XS + ((b * 2 + ck) * 2 + 1) * 4000;
        #pragma unroll
        for (int mt = 0; mt < 4; ++mt) {
          int pos = (mt * 2 + arow + dr) * 10 + acol + dc;
          short8 ah = *(const short8*)(XH + pos * 40 + q * 8);
          short8 al = *(const short8*)(XL + pos * 40 + q * 8);
          #pragma unroll
          for (int nt = 0; nt < 4; ++nt) {
            acc[b][mt][nt] = __builtin_amdgcn_mfma_f32_16x16x32_bf16(ah, bh[nt], acc[b][mt][nt], 0, 0, 0);
            acc[b][mt][nt] = __builtin_amdgcn_mfma_f32_16x16x32_bf16(al, bh[nt], acc[b][mt][nt], 0, 0, 0);
            acc[b][mt][nt] = __builtin_amdgcn_mfma_f32_16x16x32_bf16(ah, bl[nt], acc[b][mt][nt], 0, 0, 0);
          }
        }
      }
    }
  }

  // --- epilogue per batch: acc -> V (BN1+ReLU) -> fp32 1x1 + BN2 + filter ---
  #pragma unroll
  for (int b = 0; b < 2; ++b) {
    __syncthreads();   // staging (b=0) or previous V reads (b=1) complete
    #pragma unroll
    for (int mt = 0; mt < 4; ++mt) {
      #pragma unroll
      for (int nt = 0; nt < 4; ++nt) {
        int co = nt * 16 + lm;
        float A = A1s[co], Cc = C1s[co];
        #pragma unroll
        for (int r = 0; r < 4; ++r) {
          int p = mt * 16 + q * 4 + r;               // pixel within phase (8x8)
          int ur = 2 * (p >> 3) + pr, uc = 2 * (p & 7) + pc;
          V[(ur * 16 + uc) * 65 + co] = fmaxf(fmaf(A, acc[b][mt][nt][r], Cc), 0.f);
        }
      }
    }
    __syncthreads();
    {
      float a2[8];
      #pragma unroll
      for (int c2 = 0; c2 < 8; ++c2) a2[c2] = 0.f;
      const float* vp = &V[tid * 65];
      for (int co = 0; co < 64; ++co) {
        float xv = vp[co];
        #pragma unroll
        for (int c2 = 0; c2 < 8; ++c2) a2[c2] = fmaf(w2s[c2 * 64 + co], xv, a2[c2]);
      }
      int ur = tid >> 4, uc = tid & 15;
      int batch = bz * 2 + b;
      #pragma unroll
      for (int c2 = 0; c2 < 8; ++c2) {
        float y = fmaf(s2s[c2], a2[c2], sh2s[c2]);
        float o = (y > 1.0f) ? y : 0.f;
        xf[((batch * 8 + c2) * 256 + by * 16 + ur) * 256 + bx * 16 + uc] = o;
      }
    }
  }
}

// ---------------------------------------------------------------------------
// k_fix v3 helpers (proven R9).
// ---------------------------------------------------------------------------
template<int S_IS_DR>
__device__ __forceinline__ void fix_loop(const float* __restrict__ Ecom,
                                         const float* __restrict__ Xs,
                                         int base, float acc[8]) {
  for (int ci = 0; ci < 64; ++ci) {
    const float* xsrow = Xs + ci * 60;
    float run0[12], run1[12], run2[12];
    #pragma unroll
    for (int j = 0; j < 3; ++j) {
      ((float4*)run0)[j] = ((const float4*)(xsrow + base))[j];
      ((float4*)run1)[j] = ((const float4*)(xsrow + 20 + base))[j];
      ((float4*)run2)[j] = ((const float4*)(xsrow + 40 + base))[j];
    }
    float wt[9];
    #pragma unroll
    for (int tap = 0; tap < 9; ++tap) wt[tap] = Ecom[(ci * 9 + tap) * 64];
    #pragma unroll
    for (int tap = 0; tap < 9; ++tap) {
      const int dr = tap / 3, dc = tap % 3;
      const int s = S_IS_DR ? dr : dc;
      const int d = S_IS_DR ? dc : dr;
      const float* run = (s == 0) ? run0 : ((s == 1) ? run1 : run2);
      #pragma unroll
      for (int k = 0; k < 8; ++k)
        acc[k] = fmaf(wt[tap], run[k + d], acc[k]);
    }
  }
}

__device__ __forceinline__ float corner_acc(const float* __restrict__ Ecor,
                                            const float* __restrict__ Xs,
                                            int pcor) {
  float a = 0.f;
  for (int ci = 0; ci < 64; ++ci) {
    const float* xsrow = Xs + ci * 60;
    #pragma unroll
    for (int tap = 0; tap < 9; ++tap) {
      const int dr = tap / 3, dc = tap % 3;
      a = fmaf(Ecor[(ci * 9 + tap) * 64], xsrow[dr * 20 + pcor + dc], a);
    }
  }
  return a;
}

// ---------------------------------------------------------------------------
// K2: border fixup v3 (proven R9).
// ---------------------------------------------------------------------------
__global__ __launch_bounds__(256, 1) void k_fix(
    const float* __restrict__ x, const float* __restrict__ EdgeEff,
    const float* __restrict__ b1, const float* __restrict__ g1,
    const float* __restrict__ be1, const float* __restrict__ m1,
    const float* __restrict__ v1, const float* __restrict__ w2,
    const float* __restrict__ g2, const float* __restrict__ be2,
    const float* __restrict__ m2, const float* __restrict__ v2,
    float* __restrict__ xf)
{
  __shared__ __align__(16) float Xs[64 * 60];   // [ci][slot3][fast20]
  __shared__ float w2s[512];
  __shared__ float A1s[64], C1s[64];
  __shared__ float s2s[8], sh2s[8];

  const int tid = threadIdx.x;
  const int seg = blockIdx.x, line = blockIdx.y, bz = blockIdx.z;
  const bool is01 = (line < 2);

  for (int i = tid; i < 512; i += 256) w2s[i] = w2[i];
  if (tid < 64) {
    float sc = g1[tid] * rsqrtf(v1[tid] + EPS);
    A1s[tid] = sc;
    C1s[tid] = sc * (b1[tid] - m1[tid]) + be1[tid];
  }
  if (tid < 8) {
    float sc = g2[tid] * rsqrtf(v2[tid] + EPS);
    s2s[tid] = sc;
    sh2s[tid] = be2[tid] - m2[tid] * sc;
  }

  const int base0 = seg * 16 - 1;
  for (int e = tid; e < 3840; e += 256) {
    int f = e % 20;
    int slot = (e / 20) % 3;
    int ci = e / 60;
    int row, col;
    if (is01) { row = (line == 0 ? 0 : 125) + slot; col = min(max(base0 + f, 0), 127); }
    else      { col = (line == 2 ? 0 : 125) + slot; row = min(max(base0 + f, 0), 127); }
    Xs[e] = x[(size_t)(bz * 64 + ci) * 16384 + row * 128 + col];
  }
  __syncthreads();

  const int w = tid >> 6, co = tid & 63;
  const int par = w & 1;
  const int base = 8 * (w >> 1);

  int setcom;
  if (line == 0)      setcom = 8 | par;
  else if (line == 1) setcom = 12 | par;
  else if (line == 2) setcom = (par << 2) | 2;
  else                setcom = (par << 2) | 3;

  int uu[8];
  #pragma unroll
  for (int k = 0; k < 8; ++k) uu[k] = seg * 32 + 16 * (w >> 1) + 2 * k + par;

  float acc[8] = {0.f, 0.f, 0.f, 0.f, 0.f, 0.f, 0.f, 0.f};
  const float* Ecom = EdgeEff + setcom * 36864 + co;

  if (is01) fix_loop<1>(Ecom, Xs, base, acc);
  else      fix_loop<0>(Ecom, Xs, base, acc);

  if (is01 && seg == 0 && w == 0) {
    const float* Ecor = EdgeEff + ((line == 0) ? 10 : 14) * 36864 + co;
    acc[0] = corner_acc(Ecor, Xs, 1);
  }
  if (is01 && seg == 7 && w == 3) {
    const float* Ecor = EdgeEff + ((line == 0) ? 11 : 15) * 36864 + co;
    acc[7] = corner_acc(Ecor, Xs, 14);
  }

  #pragma unroll
  for (int k = 0; k < 8; ++k) {
    float v = fmaxf(fmaf(A1s[co], acc[k], C1s[co]), 0.f);
    float part[8];
    #pragma unroll
    for (int c2 = 0; c2 < 8; ++c2) part[c2] = w2s[c2 * 64 + co] * v;
    #pragma unroll
    for (int m = 1; m < 64; m <<= 1) {
      #pragma unroll
      for (int c2 = 0; c2 < 8; ++c2) part[c2] += __shfl_xor(part[c2], m, 64);
    }
    bool valid = is01 || (uu[k] >= 1 && uu[k] <= 254);
    if (co < 8 && valid) {
      float y = fmaf(s2s[co], part[co], sh2s[co]);
      float o = (y > 1.0f) ? y : 0.f;
      int R = (line == 0) ? 0 : (line == 1) ? 255 : uu[k];
      int C = (line == 2) ? 0 : (line == 3) ? 255 : uu[k];
      xf[((bz * 8 + co) * 256 + R) * 256 + C] = o;
    }
  }
}

// ---------------------------------------------------------------------------
// K3: fused separable 5x5 window-sum + row-max; 16-row chunks (proven R9).
// ---------------------------------------------------------------------------
__global__ __launch_bounds__(256) void k_sep(const float* __restrict__ xf,
                                             float* __restrict__ ws,
                                             float* __restrict__ rm) {
  __shared__ float bufx[20 * 256];
  __shared__ float bufr[20 * 256];
  const int plane = blockIdx.x >> 4;
  const int r0 = (blockIdx.x & 15) * 16;
  const int t = threadIdx.x;
  const float* xp = xf + plane * 65536;

  for (int i = t; i < 20 * 256; i += 256) {
    int rr = r0 - 2 + (i >> 8);
    bufx[i] = ((unsigned)rr < 256u) ? xp[(rr << 8) | (i & 255)] : 0.f;
  }
  __syncthreads();

  #pragma unroll 4
  for (int i = 0; i < 20; ++i) {
    const float* row = bufx + i * 256;
    float s = 0.f;
    #pragma unroll
    for (int d = -2; d <= 2; ++d) {
      int cc = t + d;
      if ((unsigned)cc < 256u) s += row[cc];
    }
    bufr[i * 256 + t] = s;
  }
  __syncthreads();

  #pragma unroll 4
  for (int i = 0; i < 16; ++i) {
    int j = i + 2;
    float s = bufr[(j - 2) * 256 + t] + bufr[(j - 1) * 256 + t] + bufr[j * 256 + t] +
              bufr[(j + 1) * 256 + t] + bufr[(j + 2) * 256 + t];
    bufx[j * 256 + t] = s;
    ws[plane * 65536 + (r0 + i) * 256 + t] = s;
  }
  __syncthreads();

  #pragma unroll 4
  for (int i = 0; i < 16; ++i) {
    int j = i + 2;
    float m = -HUGE_VALF;
    #pragma unroll
    for (int d = -2; d <= 2; ++d) {
      int cc = t + d;
      if ((unsigned)cc < 256u) m = fmaxf(m, bufx[j * 256 + cc]);
    }
    rm[plane * 65536 + (r0 + i) * 256 + t] = m;
  }
}

// ---------------------------------------------------------------------------
// K4: per-(plane, 32-row chunk) NMS mask + stable top-8 candidates (proven R9).
// ---------------------------------------------------------------------------
__global__ __launch_bounds__(256) void k_cand(const float* __restrict__ ws,
                                              const float* __restrict__ rm,
                                              float* __restrict__ candv,
                                              int* __restrict__ candi) {
  __shared__ float cv[256 * 8];
  __shared__ int cidx[256 * 8];
  const int t = threadIdx.x;
  const int plane = blockIdx.x >> 3;
  const int r0 = (blockIdx.x & 7) * 32;
  const float* wsp = ws + plane * 65536;
  const float* rmp = rm + plane * 65536;

  float bv[8]; int bi[8];
  #pragma unroll
  for (int k = 0; k < 8; ++k) { bv[k] = -HUGE_VALF; bi[k] = 0x7fffffff; }

  float w0 = (r0 >= 2) ? rmp[(r0 - 2) * 256 + t] : -HUGE_VALF;
  float w1v = (r0 >= 1) ? rmp[(r0 - 1) * 256 + t] : -HUGE_VALF;
  float w2v = rmp[r0 * 256 + t];
  float w3v = rmp[(r0 + 1) * 256 + t];
  for (int r = r0; r < r0 + 32; ++r) {
    float w4v = (r + 2 < 256) ? rmp[(r + 2) * 256 + t] : -HUGE_VALF;
    float mp = fmaxf(fmaxf(fmaxf(w0, w1v), fmaxf(w2v, w3v)), w4v);
    float wsv = wsp[r * 256 + t];
    float mv = (wsv == mp) ? wsv : 0.f;
    int e = (r << 8) | t;
    if (better(mv, e, bv[7], bi[7])) {
      bv[7] = mv; bi[7] = e;
      #pragma unroll
      for (int k = 7; k > 0; --k) {
        if (better(bv[k], bi[k], bv[k - 1], bi[k - 1])) {
          float tv = bv[k]; bv[k] = bv[k - 1]; bv[k - 1] = tv;
          int ti = bi[k]; bi[k] = bi[k - 1]; bi[k - 1] = ti;
        }
      }
    }
    w0 = w1v; w1v = w2v; w2v = w3v; w3v = w4v;
  }

  #pragma unroll
  for (int k = 0; k < 8; ++k) { cv[t * 8 + k] = bv[k]; cidx[t * 8 + k] = bi[k]; }
  __syncthreads();

  for (int s = 128; s >= 1; s >>= 1) {
    if (t < s) {
      float ov[8]; int oi[8];
      int ia = 0, ib = 0;
      #pragma unroll
      for (int k = 0; k < 8; ++k) {
        float va = cv[t * 8 + ia];       int xa = cidx[t * 8 + ia];
        float vb = cv[(t + s) * 8 + ib]; int xb = cidx[(t + s) * 8 + ib];
        if (better(va, xa, vb, xb)) { ov[k] = va; oi[k] = xa; ++ia; }
        else                        { ov[k] = vb; oi[k] = xb; ++ib; }
      }
      #pragma unroll
      for (int k = 0; k < 8; ++k) { cv[t * 8 + k] = ov[k]; cidx[t * 8 + k] = oi[k]; }
    }
    __syncthreads();
  }

  if (t < 8) {
    candv[blockIdx.x * 8 + t] = cv[t];
    candi[blockIdx.x * 8 + t] = cidx[t];
  }
}

// ---------------------------------------------------------------------------
// K5: merge 8x8 candidates per plane, extract patches and positions.
// ---------------------------------------------------------------------------
__global__ __launch_bounds__(256) void k_final(const float* __restrict__ candv,
                                               const int* __restrict__ candi,
                                               const float* __restrict__ xf,
                                               float* __restrict__ patches,
                                               float* __restrict__ pos) {
  __shared__ float cvs[64];
  __shared__ int cis[64];
  __shared__ int fidx[8];
  const int t = threadIdx.x;
  const int plane = blockIdx.x;

  if (t < 64) { cvs[t] = candv[plane * 64 + t]; cis[t] = candi[plane * 64 + t]; }
  __syncthreads();
  if (t < 64) {
    float v = cvs[t]; int i = cis[t];
    int rank = 0;
    for (int m = 0; m < 64; ++m)
      if (better(cvs[m], cis[m], v, i)) ++rank;
    if (rank < 8) fidx[rank] = i;
  }
  __syncthreads();

  const float* xfp = xf + plane * 65536;
  if (t < 200) {
    int n = t / 25, e = t % 25;
    int kr = e / 5, kc = e % 5;
    int idx = fidx[n];
    int h = idx >> 8, w = idx & 255;
    int rr = h - 2 + kr, cc = w - 2 + kc;
    float v = ((unsigned)rr < 256u && (unsigned)cc < 256u) ? xfp[rr * 256 + cc] : 0.f;
    patches[plane * 200 + t] = v;
  } else if (t < 232) {
    int qq = t - 200;
    int n = qq >> 2, k = qq & 3;
    int idx = fidx[n];
    int h = idx >> 8, w = idx & 255;
    int val;
    if (k == 0)      val = min(max(w - 2, 0), 255);
    else if (k == 1) val = min(max(h - 2, 0), 255);
    else if (k == 2) val = min(max(w + 2, 0), 255);
    else             val = min(max(h + 2, 0), 255);
    pos[plane * 32 + qq] = (float)val;
  }
}

// ---------------------------------------------------------------------------
extern "C" void kernel_launch(void* const* d_in, const int* in_sizes, int n_in,
                              void* d_out, int out_size, void* d_ws, size_t ws_size,
                              hipStream_t stream) {
  (void)in_sizes; (void)n_in; (void)out_size; (void)ws_size;
  const float* x   = (const float*)d_in[0];
  const float* w1  = (const float*)d_in[1];
  const float* b1  = (const float*)d_in[2];
  const float* g1  = (const float*)d_in[3];
  const float* be1 = (const float*)d_in[4];
  const float* m1  = (const float*)d_in[5];
  const float* v1  = (const float*)d_in[6];
  const float* w2  = (const float*)d_in[7];
  const float* g2  = (const float*)d_in[8];
  const float* be2 = (const float*)d_in[9];
  const float* m2  = (const float*)d_in[10];
  const float* v2  = (const float*)d_in[11];

  float* out = (float*)d_out;
  const int PLANE = 8 * 8 * 256 * 256;   // 4,194,304
  float* xf   = (float*)d_ws;
  float* bufA = xf + PLANE;              // rm; prep tables live here pre-k_sep
  float* bufB = bufA + PLANE;            // window sums
  float* candv = bufB + PLANE;           // 4096 floats
  int*   candi = (int*)(candv + 4096);   // 4096 ints
  unsigned short* Wphase = (unsigned short*)bufA;   // 576 KB
  float* EdgeEff = bufA + 147456;                   // 2.25 MB

  k_wprep<<<2880, 256, 0, stream>>>(w1, Wphase, EdgeEff);
  k_front<<<dim3(16, 16, 4), 256, 0, stream>>>(x, Wphase, b1, g1, be1, m1, v1,
                                               w2, g2, be2, m2, v2, xf);
  k_fix<<<dim3(8, 4, 8), 256, 0, stream>>>(x, EdgeEff, b1, g1, be1, m1, v1,
                                           w2, g2, be2, m2, v2, xf);
  k_sep<<<1024, 256, 0, stream>>>(xf, bufB, bufA);
  k_cand<<<512, 256, 0, stream>>>(bufB, bufA, candv, candi);
  k_final<<<64, 256, 0, stream>>>(candv, candi, xf, out, out + 12800);
}